// Round 4
// baseline (351.473 us; speedup 1.0000x reference)
//
#include <hip/hip_runtime.h>
#include <stdint.h>

#define V_   6890
#define N3   20670     // 3*V
#define NPAD 20736     // 81*256 padded rows for BextT
#define J_   24
#define NB_  10
#define KP   207       // pose-feature K
#define KE   224       // extended K: 207 pose + 10 shape + 1 template + 6 zero

typedef __attribute__((ext_vector_type(8))) short bf16x8;
typedef __attribute__((ext_vector_type(4))) float f32x4;

__device__ __forceinline__ float bf2f(ushort u) {
    union { uint32_t u; float f; } cv; cv.u = ((uint32_t)u) << 16; return cv.f;
}
__device__ __forceinline__ ushort f2bf(float f) {
    union { float f; uint32_t u; } cv; cv.f = f;
    uint32_t u = cv.u;
    u += 0x7FFFu + ((u >> 16) & 1u);   // round-to-nearest-even
    return (ushort)(u >> 16);
}

// ---------------------------------------------------------------------------
// K0: per-array dtype detection (insurance; evidence says all fp32).
// Count half-words with bf16-exponent-field in [1,64): fp32 mantissa noise
// hits ~25%, genuine bf16 data ~0. flags[a]=1 -> fp32, 0 -> bf16.
// ---------------------------------------------------------------------------
struct DetArgs { const void* src[9]; int n[9]; };

__global__ __launch_bounds__(256) void k_detect(DetArgs da, int* __restrict__ flags) {
    int a = blockIdx.x;
    const ushort* p = (const ushort*)da.src[a];
    int scan = da.n[a] < 8192 ? da.n[a] : 8192;
    int t = threadIdx.x;
    int cnt = 0;
    for (int i = t; i < scan; i += 256) {
        int e = (p[i] >> 7) & 0xFF;
        if (e >= 1 && e < 64) cnt++;
    }
    __shared__ int red[256];
    red[t] = cnt;
    __syncthreads();
    for (int s = 128; s > 0; s >>= 1) {
        if (t < s) red[t] += red[t + s];
        __syncthreads();
    }
    if (t == 0) flags[a] = (red[0] >= 8) ? 1 : 0;
}

// ---------------------------------------------------------------------------
// K0b: canonicalize the 8 small float inputs to fp32 in ws, per-array flag.
// ---------------------------------------------------------------------------
struct ConvArgs { const void* src[8]; float* dst[8]; int n[8]; int fidx[8]; };

__global__ __launch_bounds__(256) void k_conv(ConvArgs a, const int* __restrict__ flags) {
    int seg = blockIdx.y;
    int i = blockIdx.x * 256 + threadIdx.x;
    if (i >= a.n[seg]) return;
    const void* s = a.src[seg];
    if (flags[a.fidx[seg]])
        a.dst[seg][i] = ((const float*)s)[i];
    else
        a.dst[seg][i] = bf2f(((const ushort*)s)[i]);
}

// ---------------------------------------------------------------------------
// K1a: JT/JS precompute:  js[j*33 + c] = sum_v Jreg[j,v]*v_template[v,c]
//                         js[j*33 + 3 + c*10 + l] = sum_v Jreg[j,v]*shapedirs[v,c,l]
// ---------------------------------------------------------------------------
__global__ __launch_bounds__(256) void k_jreg(const float* __restrict__ jreg,
                                              const float* __restrict__ vt,
                                              const float* __restrict__ sd,
                                              float* __restrict__ js) {
    int j = blockIdx.x;
    int t = threadIdx.x;
    float acc[33];
#pragma unroll
    for (int i = 0; i < 33; i++) acc[i] = 0.f;
    for (int v = t; v < V_; v += 256) {
        float w = jreg[(size_t)j * V_ + v];
        acc[0] += w * vt[v * 3 + 0];
        acc[1] += w * vt[v * 3 + 1];
        acc[2] += w * vt[v * 3 + 2];
        const float* sdv = sd + (size_t)v * 30;
#pragma unroll
        for (int i = 0; i < 30; i++) acc[3 + i] += w * sdv[i];   // idx = c*10 + l
    }
    __shared__ float red[256][33];
#pragma unroll
    for (int i = 0; i < 33; i++) red[t][i] = acc[i];
    __syncthreads();
    for (int s = 128; s > 0; s >>= 1) {
        if (t < s) {
#pragma unroll
            for (int i = 0; i < 33; i++) red[t][i] += red[t + s][i];
        }
        __syncthreads();
    }
    if (t < 33) js[j * 33 + t] = red[0][t];
}

// ---------------------------------------------------------------------------
// K1b: build BextT[n][k] (bf16, NPAD x 224)
// ---------------------------------------------------------------------------
__global__ __launch_bounds__(256) void k_bext(const void* __restrict__ pdv,
                                              const float* __restrict__ c_sd,
                                              const float* __restrict__ c_vt,
                                              const int* __restrict__ flag_pd,
                                              ushort* __restrict__ bt) {
    int n = blockIdx.x * 256 + threadIdx.x;   // < NPAD by construction
    bool valid = n < N3;
    bool fl = (*flag_pd != 0);
    const float*  pdf = (const float*)pdv;
    const ushort* pdu = (const ushort*)pdv;
    for (int k0 = 0; k0 < KE; k0 += 8) {
        union { ushort s[8]; uint4 v; } u;
#pragma unroll
        for (int i = 0; i < 8; i++) {
            int k = k0 + i;
            ushort x = 0;
            if (valid) {
                if (k < KP)              x = fl ? f2bf(pdf[(size_t)k * N3 + n])
                                                : pdu[(size_t)k * N3 + n];
                else if (k < KP + NB_)   x = f2bf(c_sd[(size_t)n * NB_ + (k - KP)]);
                else if (k == KP + NB_)  x = f2bf(c_vt[n]);
            }
            u.s[i] = x;
        }
        *(uint4*)(bt + (size_t)n * KE + k0) = u.v;
    }
}

// ---------------------------------------------------------------------------
// K2: per-batch — Rodrigues, joints, pose_feat (bf16), FK, A_rel
// ---------------------------------------------------------------------------
__global__ __launch_bounds__(64) void k_pose(const float* __restrict__ shape,
                                             const float* __restrict__ body_pose,
                                             const float* __restrict__ pelvis,
                                             const float* __restrict__ js,
                                             ushort* __restrict__ pfext,
                                             float* __restrict__ arel,
                                             int Breal) {
    int b = blockIdx.x;
    int t = threadIdx.x;
    if (b >= Breal) {
        uint32_t* pz = (uint32_t*)(pfext + (size_t)b * KE);
        for (int i = t; i < KE / 2; i += 64) pz[i] = 0;
        return;
    }
    __shared__ float Rs[24][9];
    __shared__ float Js[24][3];
    __shared__ float As[24][12];

    if (t < 24) {
        float rx, ry, rz;
        if (t == 0) {
            rx = pelvis[b * 3 + 0]; ry = pelvis[b * 3 + 1]; rz = pelvis[b * 3 + 2];
        } else {
            const float* p = body_pose + ((size_t)b * 23 + (t - 1)) * 3;
            rx = p[0]; ry = p[1]; rz = p[2];
        }
        float th = sqrtf(rx * rx + ry * ry + rz * rz + 1e-8f);
        float inv = 1.f / th;
        float x = rx * inv, y = ry * inv, z = rz * inv;
        float c = cosf(th), s = sinf(th), omc = 1.f - c;
        float R[9];
        R[0] = c + omc * x * x;     R[1] = omc * x * y - s * z; R[2] = omc * x * z + s * y;
        R[3] = omc * y * x + s * z; R[4] = c + omc * y * y;     R[5] = omc * y * z - s * x;
        R[6] = omc * z * x - s * y; R[7] = omc * z * y + s * x; R[8] = c + omc * z * z;
#pragma unroll
        for (int e = 0; e < 9; e++) Rs[t][e] = R[e];

        const float* jsj = js + t * 33;
        float sh[10];
#pragma unroll
        for (int l = 0; l < 10; l++) sh[l] = shape[b * 10 + l];
#pragma unroll
        for (int c2 = 0; c2 < 3; c2++) {
            float a = jsj[c2];
#pragma unroll
            for (int l = 0; l < 10; l++) a += sh[l] * jsj[3 + c2 * 10 + l];
            Js[t][c2] = a;
        }
        ushort* pf = pfext + (size_t)b * KE;
        if (t >= 1) {
#pragma unroll
            for (int e = 0; e < 9; e++) {
                float v = R[e] - ((e == 0 || e == 4 || e == 8) ? 1.f : 0.f);
                pf[(t - 1) * 9 + e] = f2bf(v);
            }
        } else {
            for (int l = 0; l < 10; l++) pf[KP + l] = f2bf(sh[l]);
            pf[KP + NB_] = 0x3F80;                                   // 1.0 bf16
            for (int k = KP + NB_ + 1; k < KE; k++) pf[k] = 0;
        }
    }
    __syncthreads();

    if (t < 12) {
        int row = t >> 2, col = t & 3;
        As[0][t] = (col < 3) ? Rs[0][row * 3 + col] : Js[0][row];
    }
    __syncthreads();
    const int par[24] = {-1,0,0,0,1,2,3,4,5,6,7,8,9,9,9,12,13,14,16,17,18,19,20,21};
#pragma unroll 1
    for (int j = 1; j < 24; j++) {
        int p = par[j];
        float val = 0.f;
        if (t < 12) {
            int row = t >> 2, col = t & 3;
            if (col < 3) {
                val = As[p][row * 4 + 0] * Rs[j][0 * 3 + col]
                    + As[p][row * 4 + 1] * Rs[j][1 * 3 + col]
                    + As[p][row * 4 + 2] * Rs[j][2 * 3 + col];
            } else {
                float relx = Js[j][0] - Js[p][0];
                float rely = Js[j][1] - Js[p][1];
                float relz = Js[j][2] - Js[p][2];
                val = As[p][row * 4 + 0] * relx + As[p][row * 4 + 1] * rely
                    + As[p][row * 4 + 2] * relz + As[p][row * 4 + 3];
            }
        }
        __syncthreads();
        if (t < 12) As[j][t] = val;
        __syncthreads();
    }
    if (t < 24) {
        float* o = arel + ((size_t)b * 24 + t) * 12;
#pragma unroll
        for (int row = 0; row < 3; row++) {
            float r0 = As[t][row * 4 + 0], r1 = As[t][row * 4 + 1], r2 = As[t][row * 4 + 2];
            o[row * 4 + 0] = r0; o[row * 4 + 1] = r1; o[row * 4 + 2] = r2;
            o[row * 4 + 3] = As[t][row * 4 + 3] - (r0 * Js[t][0] + r1 * Js[t][1] + r2 * Js[t][2]);
        }
    }
}

// ---------------------------------------------------------------------------
// K3: MFMA GEMM  v_posed[b][n] = sum_k pfext[b][k] * BextT[n][k]
// -> d_out as FP32 (staging; LBS rewrites in place).
// ---------------------------------------------------------------------------
__global__ __launch_bounds__(256) void k_gemm(const ushort* __restrict__ bt,
                                              const ushort* __restrict__ pfext,
                                              float* __restrict__ out,
                                              int Breal) {
    int lane = threadIdx.x & 63;
    int wv   = threadIdx.x >> 6;
    int quad = lane >> 4;
    int m    = lane & 15;
    int nbase = blockIdx.x * 256 + wv * 64;
    int bbase = blockIdx.y * 32;

    f32x4 acc[4][2];
#pragma unroll
    for (int f = 0; f < 4; f++)
#pragma unroll
        for (int g = 0; g < 2; g++) acc[f][g] = (f32x4){0.f, 0.f, 0.f, 0.f};

    const ushort* aptr[4];
#pragma unroll
    for (int f = 0; f < 4; f++)
        aptr[f] = bt + (size_t)(nbase + f * 16 + m) * KE + quad * 8;
    const ushort* bptr[2];
#pragma unroll
    for (int g = 0; g < 2; g++)
        bptr[g] = pfext + (size_t)(bbase + g * 16 + m) * KE + quad * 8;

#pragma unroll
    for (int ks = 0; ks < 7; ks++) {
        bf16x8 a[4], bb[2];
#pragma unroll
        for (int f = 0; f < 4; f++) a[f] = *(const bf16x8*)(aptr[f] + ks * 32);
#pragma unroll
        for (int g = 0; g < 2; g++) bb[g] = *(const bf16x8*)(bptr[g] + ks * 32);
#pragma unroll
        for (int f = 0; f < 4; f++)
#pragma unroll
            for (int g = 0; g < 2; g++)
                acc[f][g] = __builtin_amdgcn_mfma_f32_16x16x32_bf16(a[f], bb[g], acc[f][g], 0, 0, 0);
    }

    // D layout: col(lane&15) -> b, row(quad*4+reg) -> n. n0 multiple of 4.
#pragma unroll
    for (int f = 0; f < 4; f++)
#pragma unroll
        for (int g = 0; g < 2; g++) {
            int n0 = nbase + f * 16 + quad * 4;
            int b  = bbase + g * 16 + m;
            if (b >= Breal) continue;
            float* o = out + (size_t)b * N3 + n0;
            if (n0 < N3) {                       // covers n0, n0+1 (N3 even)
                float2 lo = make_float2(acc[f][g][0], acc[f][g][1]);
                *(float2*)(o) = lo;              // 8B aligned
            }
            if (n0 + 2 < N3) {
                float2 hi = make_float2(acc[f][g][2], acc[f][g][3]);
                *(float2*)(o + 2) = hi;
            }
        }
}

// ---------------------------------------------------------------------------
// K4: LBS, in place on d_out (fp32)
// ---------------------------------------------------------------------------
__global__ __launch_bounds__(256) void k_lbs(float* __restrict__ vert,
                                             const float* __restrict__ arel,
                                             const float* __restrict__ w,
                                             const float* __restrict__ trans) {
    int b = blockIdx.y;
    int v = blockIdx.x * 256 + threadIdx.x;
    if (v >= V_) return;
    float* pv = vert + (size_t)b * N3 + (size_t)v * 3;
    float p0 = pv[0], p1 = pv[1], p2 = pv[2];

    float wl[24];
    const float4* wp = (const float4*)(w + (size_t)v * 24);
#pragma unroll
    for (int q = 0; q < 6; q++) {
        float4 f4 = wp[q];
        wl[q * 4 + 0] = f4.x; wl[q * 4 + 1] = f4.y; wl[q * 4 + 2] = f4.z; wl[q * 4 + 3] = f4.w;
    }

    const float* A = arel + (size_t)b * 288;
    float acc[12];
#pragma unroll
    for (int e = 0; e < 12; e++) acc[e] = 0.f;
#pragma unroll
    for (int j = 0; j < 24; j++) {
        float wj = wl[j];
        const float* Aj = A + j * 12;
#pragma unroll
        for (int e = 0; e < 12; e++) acc[e] += wj * Aj[e];
    }
    float ox = acc[0] * p0 + acc[1] * p1 + acc[2]  * p2 + acc[3]  + trans[b * 3 + 0];
    float oy = acc[4] * p0 + acc[5] * p1 + acc[6]  * p2 + acc[7]  + trans[b * 3 + 1];
    float oz = acc[8] * p0 + acc[9] * p1 + acc[10] * p2 + acc[11] + trans[b * 3 + 2];
    pv[0] = ox; pv[1] = oy; pv[2] = oz;
}

// ---------------------------------------------------------------------------
extern "C" void kernel_launch(void* const* d_in, const int* in_sizes, int n_in,
                              void* d_out, int out_size, void* d_ws, size_t ws_size,
                              hipStream_t stream) {
    const void* src[9];
    for (int i = 0; i < 9; i++) src[i] = d_in[i];
    float* out = (float*)d_out;

    int B    = in_sizes[0] / NB_;          // batch from shape (B,10)
    int Bpad = (B + 31) & ~31;

    char* ws = (char*)d_ws;
    size_t off = 0;
    auto alloc = [&](size_t bytes) { char* p = ws + off; off += (bytes + 255) & ~(size_t)255; return p; };
    int*    flags   = (int*)   alloc(9 * 4);
    float*  js      = (float*) alloc(24 * 33 * 4);
    float*  c_shape = (float*) alloc((size_t)in_sizes[0] * 4);
    float*  c_bpose = (float*) alloc((size_t)in_sizes[1] * 4);
    float*  c_pelv  = (float*) alloc((size_t)in_sizes[2] * 4);
    float*  c_trans = (float*) alloc((size_t)in_sizes[3] * 4);
    float*  c_vt    = (float*) alloc((size_t)in_sizes[4] * 4);
    float*  c_sd    = (float*) alloc((size_t)in_sizes[5] * 4);
    float*  c_lw    = (float*) alloc((size_t)in_sizes[7] * 4);
    float*  c_jr    = (float*) alloc((size_t)in_sizes[8] * 4);
    ushort* pfext   = (ushort*)alloc((size_t)Bpad * KE * 2);
    float*  arel    = (float*) alloc((size_t)B * 288 * 4);
    ushort* bt      = (ushort*)alloc((size_t)NPAD * KE * 2);

    DetArgs da;
    for (int i = 0; i < 9; i++) { da.src[i] = src[i]; da.n[i] = in_sizes[i]; }
    k_detect<<<9, 256, 0, stream>>>(da, flags);

    ConvArgs ca;
    const int segsrc[8] = {0, 1, 2, 3, 4, 5, 7, 8};
    float* dsts[8] = {c_shape, c_bpose, c_pelv, c_trans, c_vt, c_sd, c_lw, c_jr};
    int maxn = 0;
    for (int s = 0; s < 8; s++) {
        ca.src[s] = src[segsrc[s]]; ca.dst[s] = dsts[s];
        ca.n[s] = in_sizes[segsrc[s]]; ca.fidx[s] = segsrc[s];
        if (ca.n[s] > maxn) maxn = ca.n[s];
    }
    k_conv<<<dim3((maxn + 255) / 256, 8), 256, 0, stream>>>(ca, flags);

    k_jreg<<<24, 256, 0, stream>>>(c_jr, c_vt, c_sd, js);
    k_bext<<<NPAD / 256, 256, 0, stream>>>(src[6], c_sd, c_vt, flags + 6, bt);
    k_pose<<<Bpad, 64, 0, stream>>>(c_shape, c_bpose, c_pelv, js, pfext, arel, B);
    k_gemm<<<dim3(NPAD / 256, Bpad / 32), 256, 0, stream>>>(bt, pfext, out, B);
    k_lbs<<<dim3((V_ + 255) / 256, B), 256, 0, stream>>>(out, arel, c_lw, c_trans);
}

// Round 5
// 296.303 us; speedup vs baseline: 1.1862x; 1.1862x over previous
//
#include <hip/hip_runtime.h>
#include <stdint.h>

#define V_   6890
#define N3   20670     // 3*V
#define NPAD 20736     // 81*256 padded rows for BextT
#define J_   24
#define NB_  10
#define KP   207       // pose-feature K
#define KE   224       // extended K: 207 pose + 10 shape + 1 template + 6 zero

typedef __attribute__((ext_vector_type(8))) short bf16x8;
typedef __attribute__((ext_vector_type(4))) float f32x4;

__device__ __forceinline__ float bf2f(ushort u) {
    union { uint32_t u; float f; } cv; cv.u = ((uint32_t)u) << 16; return cv.f;
}
__device__ __forceinline__ ushort f2bf(float f) {
    union { float f; uint32_t u; } cv; cv.f = f;
    uint32_t u = cv.u;
    u += 0x7FFFu + ((u >> 16) & 1u);   // round-to-nearest-even
    return (ushort)(u >> 16);
}

// ---------------------------------------------------------------------------
// K1a: JT/JS partial sums over v-chunks of 512:
//   jsp[(j*14+c)*33 + {c3}]        = sum_v Jreg[j,v]*v_template[v,c3]
//   jsp[(j*14+c)*33 + 3 + c3*10+l] = sum_v Jreg[j,v]*shapedirs[v,c3,l]
// ---------------------------------------------------------------------------
__global__ __launch_bounds__(256) void k_jreg(const float* __restrict__ jreg,
                                              const float* __restrict__ vt,
                                              const float* __restrict__ sd,
                                              float* __restrict__ jsp) {
    int j = blockIdx.x, c = blockIdx.y;
    int t = threadIdx.x;
    float acc[33];
#pragma unroll
    for (int i = 0; i < 33; i++) acc[i] = 0.f;
#pragma unroll
    for (int it = 0; it < 2; it++) {
        int v = c * 512 + it * 256 + t;
        if (v < V_) {
            float w = jreg[(size_t)j * V_ + v];
            acc[0] += w * vt[v * 3 + 0];
            acc[1] += w * vt[v * 3 + 1];
            acc[2] += w * vt[v * 3 + 2];
            const float* sdv = sd + (size_t)v * 30;
#pragma unroll
            for (int i = 0; i < 30; i++) acc[3 + i] += w * sdv[i];
        }
    }
    __shared__ float red[256][33];
#pragma unroll
    for (int i = 0; i < 33; i++) red[t][i] = acc[i];
    __syncthreads();
    for (int s = 128; s > 0; s >>= 1) {
        if (t < s) {
#pragma unroll
            for (int i = 0; i < 33; i++) red[t][i] += red[t + s][i];
        }
        __syncthreads();
    }
    if (t < 33) jsp[(size_t)(j * 14 + c) * 33 + t] = red[0][t];
}

// K1a2: reduce 14 partials -> js[24*33]
__global__ __launch_bounds__(832) void k_jred(const float* __restrict__ jsp,
                                              float* __restrict__ js) {
    int t = threadIdx.x;
    if (t >= 792) return;
    int j = t / 33, i = t % 33;
    float s = 0.f;
#pragma unroll
    for (int c = 0; c < 14; c++) s += jsp[(size_t)(j * 14 + c) * 33 + i];
    js[t] = s;
}

// ---------------------------------------------------------------------------
// K1b: build BextT[n][k] (bf16, NPAD x 224). Grid (81, 28): 8 k per thread.
// ---------------------------------------------------------------------------
__global__ __launch_bounds__(256) void k_bext(const float* __restrict__ pd,
                                              const float* __restrict__ sd,
                                              const float* __restrict__ vt,
                                              ushort* __restrict__ bt) {
    int n  = blockIdx.x * 256 + threadIdx.x;   // < NPAD
    int k0 = blockIdx.y * 8;
    bool valid = n < N3;
    union { ushort s[8]; uint4 v; } u;
#pragma unroll
    for (int i = 0; i < 8; i++) {
        int k = k0 + i;
        float x = 0.f;
        if (valid) {
            if (k < KP)              x = pd[(size_t)k * N3 + n];
            else if (k < KP + NB_)   x = sd[(size_t)n * NB_ + (k - KP)];
            else if (k == KP + NB_)  x = vt[n];
        }
        u.s[i] = f2bf(x);
    }
    *(uint4*)(bt + (size_t)n * KE + k0) = u.v;   // 16B aligned
}

// ---------------------------------------------------------------------------
// K2: per-batch — Rodrigues, joints, pose_feat (bf16), FK, A_rel
// ---------------------------------------------------------------------------
__global__ __launch_bounds__(64) void k_pose(const float* __restrict__ shape,
                                             const float* __restrict__ body_pose,
                                             const float* __restrict__ pelvis,
                                             const float* __restrict__ js,
                                             ushort* __restrict__ pfext,
                                             float* __restrict__ arel,
                                             int Breal) {
    int b = blockIdx.x;
    int t = threadIdx.x;
    if (b >= Breal) {
        uint32_t* pz = (uint32_t*)(pfext + (size_t)b * KE);
        for (int i = t; i < KE / 2; i += 64) pz[i] = 0;
        return;
    }
    __shared__ float Rs[24][9];
    __shared__ float Js[24][3];
    __shared__ float As[24][12];

    if (t < 24) {
        float rx, ry, rz;
        if (t == 0) {
            rx = pelvis[b * 3 + 0]; ry = pelvis[b * 3 + 1]; rz = pelvis[b * 3 + 2];
        } else {
            const float* p = body_pose + ((size_t)b * 23 + (t - 1)) * 3;
            rx = p[0]; ry = p[1]; rz = p[2];
        }
        float th = sqrtf(rx * rx + ry * ry + rz * rz + 1e-8f);
        float inv = 1.f / th;
        float x = rx * inv, y = ry * inv, z = rz * inv;
        float c = cosf(th), s = sinf(th), omc = 1.f - c;
        float R[9];
        R[0] = c + omc * x * x;     R[1] = omc * x * y - s * z; R[2] = omc * x * z + s * y;
        R[3] = omc * y * x + s * z; R[4] = c + omc * y * y;     R[5] = omc * y * z - s * x;
        R[6] = omc * z * x - s * y; R[7] = omc * z * y + s * x; R[8] = c + omc * z * z;
#pragma unroll
        for (int e = 0; e < 9; e++) Rs[t][e] = R[e];

        const float* jsj = js + t * 33;
        float sh[10];
#pragma unroll
        for (int l = 0; l < 10; l++) sh[l] = shape[b * 10 + l];
#pragma unroll
        for (int c2 = 0; c2 < 3; c2++) {
            float a = jsj[c2];
#pragma unroll
            for (int l = 0; l < 10; l++) a += sh[l] * jsj[3 + c2 * 10 + l];
            Js[t][c2] = a;
        }
        ushort* pf = pfext + (size_t)b * KE;
        if (t >= 1) {
#pragma unroll
            for (int e = 0; e < 9; e++) {
                float v = R[e] - ((e == 0 || e == 4 || e == 8) ? 1.f : 0.f);
                pf[(t - 1) * 9 + e] = f2bf(v);
            }
        } else {
            for (int l = 0; l < 10; l++) pf[KP + l] = f2bf(sh[l]);
            pf[KP + NB_] = 0x3F80;                                   // 1.0 bf16
            for (int k = KP + NB_ + 1; k < KE; k++) pf[k] = 0;
        }
    }
    __syncthreads();

    if (t < 12) {
        int row = t >> 2, col = t & 3;
        As[0][t] = (col < 3) ? Rs[0][row * 3 + col] : Js[0][row];
    }
    __syncthreads();
    const int par[24] = {-1,0,0,0,1,2,3,4,5,6,7,8,9,9,9,12,13,14,16,17,18,19,20,21};
#pragma unroll 1
    for (int j = 1; j < 24; j++) {
        int p = par[j];
        float val = 0.f;
        if (t < 12) {
            int row = t >> 2, col = t & 3;
            if (col < 3) {
                val = As[p][row * 4 + 0] * Rs[j][0 * 3 + col]
                    + As[p][row * 4 + 1] * Rs[j][1 * 3 + col]
                    + As[p][row * 4 + 2] * Rs[j][2 * 3 + col];
            } else {
                float relx = Js[j][0] - Js[p][0];
                float rely = Js[j][1] - Js[p][1];
                float relz = Js[j][2] - Js[p][2];
                val = As[p][row * 4 + 0] * relx + As[p][row * 4 + 1] * rely
                    + As[p][row * 4 + 2] * relz + As[p][row * 4 + 3];
            }
        }
        __syncthreads();
        if (t < 12) As[j][t] = val;
        __syncthreads();
    }
    if (t < 24) {
        float* o = arel + ((size_t)b * 24 + t) * 12;
#pragma unroll
        for (int row = 0; row < 3; row++) {
            float r0 = As[t][row * 4 + 0], r1 = As[t][row * 4 + 1], r2 = As[t][row * 4 + 2];
            o[row * 4 + 0] = r0; o[row * 4 + 1] = r1; o[row * 4 + 2] = r2;
            o[row * 4 + 3] = As[t][row * 4 + 3] - (r0 * Js[t][0] + r1 * Js[t][1] + r2 * Js[t][2]);
        }
    }
}

// ---------------------------------------------------------------------------
// K3: MFMA GEMM  v_posed[b][n] = sum_k pfext[b][k] * BextT[n][k] -> d_out fp32
// Wave tile: 64 n (4 M-frags) x 64 b (4 N-frags). Grid (81, Bpad/64).
// ---------------------------------------------------------------------------
__global__ __launch_bounds__(256) void k_gemm(const ushort* __restrict__ bt,
                                              const ushort* __restrict__ pfext,
                                              float* __restrict__ out,
                                              int Breal) {
    int lane = threadIdx.x & 63;
    int wv   = threadIdx.x >> 6;
    int quad = lane >> 4;
    int m    = lane & 15;
    int nbase = blockIdx.x * 256 + wv * 64;
    int bbase = blockIdx.y * 64;

    f32x4 acc[4][4];
#pragma unroll
    for (int f = 0; f < 4; f++)
#pragma unroll
        for (int g = 0; g < 4; g++) acc[f][g] = (f32x4){0.f, 0.f, 0.f, 0.f};

    const ushort* aptr[4];
#pragma unroll
    for (int f = 0; f < 4; f++)
        aptr[f] = bt + (size_t)(nbase + f * 16 + m) * KE + quad * 8;
    const ushort* bptr[4];
#pragma unroll
    for (int g = 0; g < 4; g++)
        bptr[g] = pfext + (size_t)(bbase + g * 16 + m) * KE + quad * 8;

#pragma unroll
    for (int ks = 0; ks < 7; ks++) {
        bf16x8 a[4], bb[4];
#pragma unroll
        for (int f = 0; f < 4; f++) a[f] = *(const bf16x8*)(aptr[f] + ks * 32);
#pragma unroll
        for (int g = 0; g < 4; g++) bb[g] = *(const bf16x8*)(bptr[g] + ks * 32);
#pragma unroll
        for (int f = 0; f < 4; f++)
#pragma unroll
            for (int g = 0; g < 4; g++)
                acc[f][g] = __builtin_amdgcn_mfma_f32_16x16x32_bf16(a[f], bb[g], acc[f][g], 0, 0, 0);
    }

    // D layout: col(lane&15) -> b, row(quad*4+reg) -> n. n0 multiple of 4.
#pragma unroll
    for (int f = 0; f < 4; f++)
#pragma unroll
        for (int g = 0; g < 4; g++) {
            int n0 = nbase + f * 16 + quad * 4;
            int b  = bbase + g * 16 + m;
            if (b >= Breal) continue;
            float* o = out + (size_t)b * N3 + n0;
            if (n0 < N3)
                *(float2*)(o) = make_float2(acc[f][g][0], acc[f][g][1]);
            if (n0 + 2 < N3)
                *(float2*)(o + 2) = make_float2(acc[f][g][2], acc[f][g][3]);
        }
}

// ---------------------------------------------------------------------------
// K4: LBS in place on d_out (fp32). Each thread owns one vertex's weights,
// loops over 16 batches (weights reused; A loads are wave-uniform -> SMEM).
// ---------------------------------------------------------------------------
__global__ __launch_bounds__(256) void k_lbs(float* __restrict__ vert,
                                             const float* __restrict__ arel,
                                             const float* __restrict__ w,
                                             const float* __restrict__ trans,
                                             int Breal) {
    int v = blockIdx.x * 256 + threadIdx.x;
    if (v >= V_) return;

    float wl[24];
    const float4* wp = (const float4*)(w + (size_t)v * 24);
#pragma unroll
    for (int q = 0; q < 6; q++) {
        float4 f4 = wp[q];
        wl[q * 4 + 0] = f4.x; wl[q * 4 + 1] = f4.y; wl[q * 4 + 2] = f4.z; wl[q * 4 + 3] = f4.w;
    }

#pragma unroll 1
    for (int bb = 0; bb < 16; bb++) {
        int b = blockIdx.y * 16 + bb;
        if (b >= Breal) break;
        float* pv = vert + (size_t)b * N3 + (size_t)v * 3;
        float p0 = pv[0], p1 = pv[1], p2 = pv[2];

        const float* A = arel + (size_t)b * 288;
        float2 ac[6];
#pragma unroll
        for (int e = 0; e < 6; e++) ac[e] = make_float2(0.f, 0.f);
#pragma unroll
        for (int j = 0; j < 24; j++) {
            float wj = wl[j];
            const float2* A2 = (const float2*)(A + j * 12);
#pragma unroll
            for (int e = 0; e < 6; e++) {
                float2 a2 = A2[e];
                ac[e].x += wj * a2.x;
                ac[e].y += wj * a2.y;
            }
        }
        float ox = ac[0].x * p0 + ac[0].y * p1 + ac[1].x * p2 + ac[1].y + trans[b * 3 + 0];
        float oy = ac[2].x * p0 + ac[2].y * p1 + ac[3].x * p2 + ac[3].y + trans[b * 3 + 1];
        float oz = ac[4].x * p0 + ac[4].y * p1 + ac[5].x * p2 + ac[5].y + trans[b * 3 + 2];
        pv[0] = ox; pv[1] = oy; pv[2] = oz;
    }
}

// ---------------------------------------------------------------------------
extern "C" void kernel_launch(void* const* d_in, const int* in_sizes, int n_in,
                              void* d_out, int out_size, void* d_ws, size_t ws_size,
                              hipStream_t stream) {
    const float* shape = (const float*)d_in[0];
    const float* bpose = (const float*)d_in[1];
    const float* pelv  = (const float*)d_in[2];
    const float* trans = (const float*)d_in[3];
    const float* vt    = (const float*)d_in[4];
    const float* sd    = (const float*)d_in[5];
    const float* pd    = (const float*)d_in[6];
    const float* lw    = (const float*)d_in[7];
    const float* jr    = (const float*)d_in[8];
    float* out = (float*)d_out;

    int B    = in_sizes[0] / NB_;          // batch from shape (B,10)
    int Bpad = (B + 63) & ~63;

    char* ws = (char*)d_ws;
    size_t off = 0;
    auto alloc = [&](size_t bytes) { char* p = ws + off; off += (bytes + 255) & ~(size_t)255; return p; };
    float*  jsp   = (float*) alloc(24 * 14 * 33 * 4);
    float*  js    = (float*) alloc(24 * 33 * 4);
    ushort* pfext = (ushort*)alloc((size_t)Bpad * KE * 2);
    float*  arel  = (float*) alloc((size_t)B * 288 * 4);
    ushort* bt    = (ushort*)alloc((size_t)NPAD * KE * 2);

    k_jreg<<<dim3(24, 14), 256, 0, stream>>>(jr, vt, sd, jsp);
    k_jred<<<1, 832, 0, stream>>>(jsp, js);
    k_bext<<<dim3(NPAD / 256, KE / 8), 256, 0, stream>>>(pd, sd, vt, bt);
    k_pose<<<Bpad, 64, 0, stream>>>(shape, bpose, pelv, js, pfext, arel, B);
    k_gemm<<<dim3(NPAD / 256, Bpad / 64), 256, 0, stream>>>(bt, pfext, out, B);
    k_lbs<<<dim3((V_ + 255) / 256, (B + 15) / 16), 256, 0, stream>>>(out, arel, lw, trans, B);
}

// Round 6
// 260.202 us; speedup vs baseline: 1.3508x; 1.1387x over previous
//
#include <hip/hip_runtime.h>
#include <stdint.h>

#define V_   6890
#define N3   20670     // 3*V
#define NPAD 20736     // 81*256 padded rows for BextT
#define VPAD 7168      // 448 v-tiles of 16, covers grid.x=14 * 512
#define J_   24
#define NB_  10
#define KP   207       // pose-feature K
#define KE   224       // extended K: 207 pose + 10 shape + 1 template + 6 zero

typedef __attribute__((ext_vector_type(8))) short bf16x8;
typedef __attribute__((ext_vector_type(4))) float f32x4;

__device__ __forceinline__ float bf2f(ushort u) {
    union { uint32_t u; float f; } cv; cv.u = ((uint32_t)u) << 16; return cv.f;
}
__device__ __forceinline__ ushort f2bf(float f) {
    union { float f; uint32_t u; } cv; cv.f = f;
    uint32_t u = cv.u;
    u += 0x7FFFu + ((u >> 16) & 1u);   // round-to-nearest-even
    return (ushort)(u >> 16);
}

// ---------------------------------------------------------------------------
// K1a: JT/JS partial sums over v-chunks of 512
// ---------------------------------------------------------------------------
__global__ __launch_bounds__(256) void k_jreg(const float* __restrict__ jreg,
                                              const float* __restrict__ vt,
                                              const float* __restrict__ sd,
                                              float* __restrict__ jsp) {
    int j = blockIdx.x, c = blockIdx.y;
    int t = threadIdx.x;
    float acc[33];
#pragma unroll
    for (int i = 0; i < 33; i++) acc[i] = 0.f;
#pragma unroll
    for (int it = 0; it < 2; it++) {
        int v = c * 512 + it * 256 + t;
        if (v < V_) {
            float w = jreg[(size_t)j * V_ + v];
            acc[0] += w * vt[v * 3 + 0];
            acc[1] += w * vt[v * 3 + 1];
            acc[2] += w * vt[v * 3 + 2];
            const float* sdv = sd + (size_t)v * 30;
#pragma unroll
            for (int i = 0; i < 30; i++) acc[3 + i] += w * sdv[i];
        }
    }
    __shared__ float red[256][33];
#pragma unroll
    for (int i = 0; i < 33; i++) red[t][i] = acc[i];
    __syncthreads();
    for (int s = 128; s > 0; s >>= 1) {
        if (t < s) {
#pragma unroll
            for (int i = 0; i < 33; i++) red[t][i] += red[t + s][i];
        }
        __syncthreads();
    }
    if (t < 33) jsp[(size_t)(j * 14 + c) * 33 + t] = red[0][t];
}

// K1a2: reduce 14 partials -> js[24*33]
__global__ __launch_bounds__(832) void k_jred(const float* __restrict__ jsp,
                                              float* __restrict__ js) {
    int t = threadIdx.x;
    if (t >= 792) return;
    int j = t / 33, i = t % 33;
    float s = 0.f;
#pragma unroll
    for (int c = 0; c < 14; c++) s += jsp[(size_t)(j * 14 + c) * 33 + i];
    js[t] = s;
}

// ---------------------------------------------------------------------------
// K1b: build BextT[n][k] (bf16, NPAD x 224). Grid (81, 28): 8 k per thread.
// ---------------------------------------------------------------------------
__global__ __launch_bounds__(256) void k_bext(const float* __restrict__ pd,
                                              const float* __restrict__ sd,
                                              const float* __restrict__ vt,
                                              ushort* __restrict__ bt) {
    int n  = blockIdx.x * 256 + threadIdx.x;   // < NPAD
    int k0 = blockIdx.y * 8;
    bool valid = n < N3;
    union { ushort s[8]; uint4 v; } u;
#pragma unroll
    for (int i = 0; i < 8; i++) {
        int k = k0 + i;
        float x = 0.f;
        if (valid) {
            if (k < KP)              x = pd[(size_t)k * N3 + n];
            else if (k < KP + NB_)   x = sd[(size_t)n * NB_ + (k - KP)];
            else if (k == KP + NB_)  x = vt[n];
        }
        u.s[i] = f2bf(x);
    }
    *(uint4*)(bt + (size_t)n * KE + k0) = u.v;   // 16B aligned
}

// ---------------------------------------------------------------------------
// K1c: lbs_weights -> bf16 hi/lo, layout [VPAD][32] (j>=24 and v>=V_ zero)
// ---------------------------------------------------------------------------
__global__ __launch_bounds__(256) void k_wbf(const float* __restrict__ lw,
                                             ushort* __restrict__ w_hi,
                                             ushort* __restrict__ w_lo) {
    int i = blockIdx.x * 256 + threadIdx.x;    // < VPAD*32
    int v = i >> 5, j = i & 31;
    float x = (j < 24 && v < V_) ? lw[(size_t)v * 24 + j] : 0.f;
    ushort hi = f2bf(x);
    w_hi[i] = hi;
    w_lo[i] = f2bf(x - bf2f(hi));
}

// ---------------------------------------------------------------------------
// K2: per-batch — Rodrigues, joints, pose_feat (bf16), FK, then write
// A_rel TRANSPOSED as bf16 hi/lo: aT[b][e*32+j] = A_rel[b][j][e] (e<12,j<24).
// ---------------------------------------------------------------------------
__global__ __launch_bounds__(64) void k_pose(const float* __restrict__ shape,
                                             const float* __restrict__ body_pose,
                                             const float* __restrict__ pelvis,
                                             const float* __restrict__ js,
                                             ushort* __restrict__ pfext,
                                             ushort* __restrict__ aT_hi,
                                             ushort* __restrict__ aT_lo,
                                             int Breal) {
    int b = blockIdx.x;
    int t = threadIdx.x;
    if (b >= Breal) {
        uint32_t* pz = (uint32_t*)(pfext + (size_t)b * KE);
        for (int i = t; i < KE / 2; i += 64) pz[i] = 0;
        return;
    }
    __shared__ float Rs[24][9];
    __shared__ float Js[24][3];
    __shared__ float As[24][12];

    if (t < 24) {
        float rx, ry, rz;
        if (t == 0) {
            rx = pelvis[b * 3 + 0]; ry = pelvis[b * 3 + 1]; rz = pelvis[b * 3 + 2];
        } else {
            const float* p = body_pose + ((size_t)b * 23 + (t - 1)) * 3;
            rx = p[0]; ry = p[1]; rz = p[2];
        }
        float th = sqrtf(rx * rx + ry * ry + rz * rz + 1e-8f);
        float inv = 1.f / th;
        float x = rx * inv, y = ry * inv, z = rz * inv;
        float c = cosf(th), s = sinf(th), omc = 1.f - c;
        float R[9];
        R[0] = c + omc * x * x;     R[1] = omc * x * y - s * z; R[2] = omc * x * z + s * y;
        R[3] = omc * y * x + s * z; R[4] = c + omc * y * y;     R[5] = omc * y * z - s * x;
        R[6] = omc * z * x - s * y; R[7] = omc * z * y + s * x; R[8] = c + omc * z * z;
#pragma unroll
        for (int e = 0; e < 9; e++) Rs[t][e] = R[e];

        const float* jsj = js + t * 33;
        float sh[10];
#pragma unroll
        for (int l = 0; l < 10; l++) sh[l] = shape[b * 10 + l];
#pragma unroll
        for (int c2 = 0; c2 < 3; c2++) {
            float a = jsj[c2];
#pragma unroll
            for (int l = 0; l < 10; l++) a += sh[l] * jsj[3 + c2 * 10 + l];
            Js[t][c2] = a;
        }
        ushort* pf = pfext + (size_t)b * KE;
        if (t >= 1) {
#pragma unroll
            for (int e = 0; e < 9; e++) {
                float v = R[e] - ((e == 0 || e == 4 || e == 8) ? 1.f : 0.f);
                pf[(t - 1) * 9 + e] = f2bf(v);
            }
        } else {
            for (int l = 0; l < 10; l++) pf[KP + l] = f2bf(sh[l]);
            pf[KP + NB_] = 0x3F80;                                   // 1.0 bf16
            for (int k = KP + NB_ + 1; k < KE; k++) pf[k] = 0;
        }
    }
    __syncthreads();

    if (t < 12) {
        int row = t >> 2, col = t & 3;
        As[0][t] = (col < 3) ? Rs[0][row * 3 + col] : Js[0][row];
    }
    __syncthreads();
    const int par[24] = {-1,0,0,0,1,2,3,4,5,6,7,8,9,9,9,12,13,14,16,17,18,19,20,21};
#pragma unroll 1
    for (int j = 1; j < 24; j++) {
        int p = par[j];
        float val = 0.f;
        if (t < 12) {
            int row = t >> 2, col = t & 3;
            if (col < 3) {
                val = As[p][row * 4 + 0] * Rs[j][0 * 3 + col]
                    + As[p][row * 4 + 1] * Rs[j][1 * 3 + col]
                    + As[p][row * 4 + 2] * Rs[j][2 * 3 + col];
            } else {
                float relx = Js[j][0] - Js[p][0];
                float rely = Js[j][1] - Js[p][1];
                float relz = Js[j][2] - Js[p][2];
                val = As[p][row * 4 + 0] * relx + As[p][row * 4 + 1] * rely
                    + As[p][row * 4 + 2] * relz + As[p][row * 4 + 3];
            }
        }
        __syncthreads();
        if (t < 12) As[j][t] = val;
        __syncthreads();
    }
    // finalize t_corr in place: As[j][x*4+3] = t - R*joint
    if (t < 24) {
        float tc[3];
#pragma unroll
        for (int row = 0; row < 3; row++) {
            float r0 = As[t][row * 4 + 0], r1 = As[t][row * 4 + 1], r2 = As[t][row * 4 + 2];
            tc[row] = As[t][row * 4 + 3] - (r0 * Js[t][0] + r1 * Js[t][1] + r2 * Js[t][2]);
        }
        As[t][3] = tc[0]; As[t][7] = tc[1]; As[t][11] = tc[2];
    }
    __syncthreads();
    // aT[e*32+j] = As[j][e], hi/lo bf16 (e<12, j<24; else 0)
    ushort* dh = aT_hi + (size_t)b * 512;
    ushort* dl = aT_lo + (size_t)b * 512;
    for (int i = t; i < 512; i += 64) {
        int e = i >> 5, j = i & 31;
        float val = (e < 12 && j < 24) ? As[j][e] : 0.f;
        ushort hi = f2bf(val);
        dh[i] = hi;
        dl[i] = f2bf(val - bf2f(hi));
    }
}

// ---------------------------------------------------------------------------
// K3: MFMA GEMM  v_posed[b][n] = sum_k pfext[b][k] * BextT[n][k] -> d_out fp32
// ---------------------------------------------------------------------------
__global__ __launch_bounds__(256) void k_gemm(const ushort* __restrict__ bt,
                                              const ushort* __restrict__ pfext,
                                              float* __restrict__ out,
                                              int Breal) {
    int lane = threadIdx.x & 63;
    int wv   = threadIdx.x >> 6;
    int quad = lane >> 4;
    int m    = lane & 15;
    int nbase = blockIdx.x * 256 + wv * 64;
    int bbase = blockIdx.y * 64;

    f32x4 acc[4][4];
#pragma unroll
    for (int f = 0; f < 4; f++)
#pragma unroll
        for (int g = 0; g < 4; g++) acc[f][g] = (f32x4){0.f, 0.f, 0.f, 0.f};

    const ushort* aptr[4];
#pragma unroll
    for (int f = 0; f < 4; f++)
        aptr[f] = bt + (size_t)(nbase + f * 16 + m) * KE + quad * 8;
    const ushort* bptr[4];
#pragma unroll
    for (int g = 0; g < 4; g++)
        bptr[g] = pfext + (size_t)(bbase + g * 16 + m) * KE + quad * 8;

#pragma unroll
    for (int ks = 0; ks < 7; ks++) {
        bf16x8 a[4], bb[4];
#pragma unroll
        for (int f = 0; f < 4; f++) a[f] = *(const bf16x8*)(aptr[f] + ks * 32);
#pragma unroll
        for (int g = 0; g < 4; g++) bb[g] = *(const bf16x8*)(bptr[g] + ks * 32);
#pragma unroll
        for (int f = 0; f < 4; f++)
#pragma unroll
            for (int g = 0; g < 4; g++)
                acc[f][g] = __builtin_amdgcn_mfma_f32_16x16x32_bf16(a[f], bb[g], acc[f][g], 0, 0, 0);
    }

#pragma unroll
    for (int f = 0; f < 4; f++)
#pragma unroll
        for (int g = 0; g < 4; g++) {
            int n0 = nbase + f * 16 + quad * 4;
            int b  = bbase + g * 16 + m;
            if (b >= Breal) continue;
            float* o = out + (size_t)b * N3 + n0;
            if (n0 < N3)
                *(float2*)(o) = make_float2(acc[f][g][0], acc[f][g][1]);
            if (n0 + 2 < N3)
                *(float2*)(o + 2) = make_float2(acc[f][g][2], acc[f][g][3]);
        }
}

// ---------------------------------------------------------------------------
// K4: MFMA LBS, in place on d_out (fp32).
// Per (16v-tile, b): Tv^T[e,v] = A_b'(16e x 32j) @ W^T(32j x 16v) via
// 3 MFMAs (hi*hi + lo*hi + hi*lo). D layout: col(lane&15)=v, row(quad*4+r)=e;
// quad q<3 holds row x=q of the 3x4 transform in acc[0..3]:
//   verts[v,q] = acc0*p0 + acc1*p1 + acc2*p2 + acc3 + trans[q].
// Wave holds 8 v-tiles' W-frags in regs, loops 8 batches (A reloaded per b).
// ---------------------------------------------------------------------------
__global__ __launch_bounds__(256) void k_lbsm(float* __restrict__ vert,
                                              const ushort* __restrict__ aT_hi,
                                              const ushort* __restrict__ aT_lo,
                                              const ushort* __restrict__ w_hi,
                                              const ushort* __restrict__ w_lo,
                                              const float* __restrict__ trans,
                                              int Breal) {
    int lane = threadIdx.x & 63;
    int wv   = threadIdx.x >> 6;
    int quad = lane >> 4;
    int m    = lane & 15;
    int tile0 = blockIdx.x * 32 + wv * 8;
    int bbase = blockIdx.y * 8;

    bf16x8 Wh[8], Wl[8];
#pragma unroll
    for (int i = 0; i < 8; i++) {
        size_t offw = (size_t)((tile0 + i) * 16 + m) * 32 + quad * 8;  // < VPAD*32
        Wh[i] = *(const bf16x8*)(w_hi + offw);
        Wl[i] = *(const bf16x8*)(w_lo + offw);
    }

#pragma unroll 1
    for (int bb = 0; bb < 8; bb++) {
        int b = bbase + bb;
        if (b >= Breal) break;
        size_t aoff = (size_t)b * 512 + m * 32 + quad * 8;
        bf16x8 Ah = *(const bf16x8*)(aT_hi + aoff);
        bf16x8 Al = *(const bf16x8*)(aT_lo + aoff);
        float tq = (quad < 3) ? trans[b * 3 + quad] : 0.f;
        float* vrow = vert + (size_t)b * N3;
#pragma unroll
        for (int i = 0; i < 8; i++) {
            int v  = (tile0 + i) * 16 + m;
            int vc = v < V_ ? v : V_ - 1;
            const float* pp = vrow + 3 * vc;
            float p0 = pp[0], p1 = pp[1], p2 = pp[2];
            f32x4 acc = (f32x4){0.f, 0.f, 0.f, 0.f};
            acc = __builtin_amdgcn_mfma_f32_16x16x32_bf16(Ah, Wh[i], acc, 0, 0, 0);
            acc = __builtin_amdgcn_mfma_f32_16x16x32_bf16(Al, Wh[i], acc, 0, 0, 0);
            acc = __builtin_amdgcn_mfma_f32_16x16x32_bf16(Ah, Wl[i], acc, 0, 0, 0);
            float res = acc[0] * p0 + acc[1] * p1 + acc[2] * p2 + acc[3] + tq;
            if (quad < 3 && v < V_)
                vrow[3 * v + quad] = res;
        }
    }
}

// ---------------------------------------------------------------------------
extern "C" void kernel_launch(void* const* d_in, const int* in_sizes, int n_in,
                              void* d_out, int out_size, void* d_ws, size_t ws_size,
                              hipStream_t stream) {
    const float* shape = (const float*)d_in[0];
    const float* bpose = (const float*)d_in[1];
    const float* pelv  = (const float*)d_in[2];
    const float* trans = (const float*)d_in[3];
    const float* vt    = (const float*)d_in[4];
    const float* sd    = (const float*)d_in[5];
    const float* pd    = (const float*)d_in[6];
    const float* lw    = (const float*)d_in[7];
    const float* jr    = (const float*)d_in[8];
    float* out = (float*)d_out;

    int B    = in_sizes[0] / NB_;          // batch from shape (B,10)
    int Bpad = (B + 63) & ~63;

    char* ws = (char*)d_ws;
    size_t off = 0;
    auto alloc = [&](size_t bytes) { char* p = ws + off; off += (bytes + 255) & ~(size_t)255; return p; };
    float*  jsp   = (float*) alloc(24 * 14 * 33 * 4);
    float*  js    = (float*) alloc(24 * 33 * 4);
    ushort* pfext = (ushort*)alloc((size_t)Bpad * KE * 2);
    ushort* aT_hi = (ushort*)alloc((size_t)B * 512 * 2);
    ushort* aT_lo = (ushort*)alloc((size_t)B * 512 * 2);
    ushort* w_hi  = (ushort*)alloc((size_t)VPAD * 32 * 2);
    ushort* w_lo  = (ushort*)alloc((size_t)VPAD * 32 * 2);
    ushort* bt    = (ushort*)alloc((size_t)NPAD * KE * 2);

    k_jreg<<<dim3(24, 14), 256, 0, stream>>>(jr, vt, sd, jsp);
    k_jred<<<1, 832, 0, stream>>>(jsp, js);
    k_bext<<<dim3(NPAD / 256, KE / 8), 256, 0, stream>>>(pd, sd, vt, bt);
    k_wbf<<<VPAD * 32 / 256, 256, 0, stream>>>(lw, w_hi, w_lo);
    k_pose<<<Bpad, 64, 0, stream>>>(shape, bpose, pelv, js, pfext, aT_hi, aT_lo, B);
    k_gemm<<<dim3(NPAD / 256, Bpad / 64), 256, 0, stream>>>(bt, pfext, out, B);
    k_lbsm<<<dim3((V_ + 511) / 512, (B + 7) / 8), 256, 0, stream>>>(out, aT_hi, aT_lo, w_hi, w_lo, trans, B);
}